// Round 3
// baseline (257.336 us; speedup 1.0000x reference)
//
#include <hip/hip_runtime.h>
#include <hip/hip_bf16.h>

// CausalSelfAttention: B=4, T=2048, D=1024, H=16, DH=64.
// Dtypes (established): inputs fp32, output fp32 (absmax thresh 0.075).
// R12: gemm1 (qkv projection) ported to 256x256 8-phase schedule (T2+T3+T4+T5):
//   8 waves (512 thr), BK=64, dbuf LDS 128KB, 4 quadrant-phases per K-tile,
//   per-phase half-tile prefetch via global_load_lds, counted vmcnt(4) at
//   tile boundaries (never 0 mid-loop), XOR-chunk swizzle (2-way-free
//   ds_read_b128), s_setprio(1) around each 16-MFMA cluster, XCD-aware
//   block swizzle. K-accumulation order identical to R11 -> bit-identical C.
// gemm2 (N=1024 -> only 128 blocks at 256^2 = 50% util) stays on 128^2 kernel.
// attn unchanged from R11.

namespace {
constexpr int kB = 4, kT = 2048, kD = 1024, kH = 16;
constexpr int kM = kB * kT;  // 8192
constexpr int kNq = 3 * kD;  // 3072
constexpr float kS = 0.180336880f;  // log2(e)/sqrt(64), folded into Q weights
}  // namespace

typedef unsigned short u16;
typedef short bf16x8 __attribute__((ext_vector_type(8)));  // 8 bf16, 4 VGPR
typedef float f32x4 __attribute__((ext_vector_type(4)));

__device__ __forceinline__ u16 f2bf(float f) {
  unsigned int u = __float_as_uint(f);
  u += 0x7fffu + ((u >> 16) & 1u);  // round-to-nearest-even
  return (u16)(u >> 16);
}
__device__ __forceinline__ unsigned int pack2(float a, float b) {
  return (unsigned int)f2bf(a) | ((unsigned int)f2bf(b) << 16);
}
// packed f32x2 -> bf16x2 in one VALU op (RNE)
__device__ __forceinline__ unsigned int cvtpk(float a, float b) {
  unsigned int r;
  asm("v_cvt_pk_bf16_f32 %0, %1, %2" : "=v"(r) : "v"(a), "v"(b));
  return r;
}

// async 16B global -> LDS (wave-uniform base + lane*16 semantics)
__device__ __forceinline__ void gload16(const u16* g, u16* l) {
  __builtin_amdgcn_global_load_lds(
      (const __attribute__((address_space(1))) unsigned int*)(uintptr_t)g,
      (__attribute__((address_space(3))) unsigned int*)(uintptr_t)l, 16, 0, 0);
}

// x fp32 -> bf16, 8 elems/thread
__global__ __launch_bounds__(256) void cvt_bf16(const float* __restrict__ x,
                                                u16* __restrict__ xb) {
  const size_t i = ((size_t)blockIdx.x * 256 + threadIdx.x) * 8;
  const float4 v0 = *(const float4*)(x + i);
  const float4 v1 = *(const float4*)(x + i + 4);
  uint4 p;
  p.x = pack2(v0.x, v0.y);
  p.y = pack2(v0.z, v0.w);
  p.z = pack2(v1.x, v1.y);
  p.w = pack2(v1.z, v1.w);
  *(uint4*)(xb + i) = p;
}

// WT[n][k] = bf16(W[k][n] * (n < nscale ? kS : 1)); W fp32 [K][N].
// 32x32 tiles via LDS. nscale folds the softmax scale into Q-columns free.
__global__ __launch_bounds__(256) void transpose_bf(const float* __restrict__ W,
                                                    u16* __restrict__ WT,
                                                    int K, int N, int nscale) {
  __shared__ float T[32][33];
  const int tid = threadIdx.x;
  const int nb = blockIdx.x * 32, kb = blockIdx.y * 32;
  const int r = tid >> 3, c = (tid & 7) * 4;
  const float4 v = *(const float4*)&W[(size_t)(kb + r) * N + nb + c];
  T[r][c + 0] = v.x;
  T[r][c + 1] = v.y;
  T[r][c + 2] = v.z;
  T[r][c + 3] = v.w;
  __syncthreads();
  const float s = (nb + r < nscale) ? kS : 1.0f;
  uint2 p;
  p.x = pack2(T[c + 0][r] * s, T[c + 1][r] * s);
  p.y = pack2(T[c + 2][r] * s, T[c + 3][r] * s);
  *(uint2*)&WT[(size_t)(nb + r) * K + kb + c] = p;
}

// ---------------------------------------------------------------------------
// 256x256 8-phase GEMM: C[m][n] = sum_k A[m][k] * BT[n][k]; bf16 in, bf16 out.
// K=1024 (16 K-tiles of BK=64). 8 waves arranged 2(M)x4(N); wave tile is
// interleaved: rows {wm*64..+64} in each 128-row half, cols {wn*32..+32} in
// each 128-col half -> quadrant (mq,nq) touches exactly one A-half + one
// B-half, enabling slot-granular prefetch.
// Staging: thread -> (row tid>>3, storage chunk tid&7); global chunk =
// (tid&7)^(row&7) so ds_read_b128 at 128B row stride is 2-way (free).
// Schedule per tile t (4 phases, double barrier each):
//   ph0: read quad(0,0) | stage BB(t+1)->nxt
//   ph1: read quad(0,1) | stage AB(t+1)->nxt
//   ph2: read quad(1,0) | stage AT(t+2)->cur  (AT slot free after ph1)
//   ph3: read quad(1,1) | stage BT(t+2)->cur  (BT slot free after ph2)
//        + boundary s_waitcnt vmcnt(4) (leaves AT,BT(t+2) in flight)
// Prologue: AT0,BT0,BB0,AB0,AT1,BT1 -> vmcnt(4).
// ---------------------------------------------------------------------------
__global__ __launch_bounds__(512, 2) void gemm256(const u16* __restrict__ A,
                                                  const u16* __restrict__ BT,
                                                  u16* __restrict__ C, int lda,
                                                  int ldc) {
  __shared__ u16 As[2][256 * 64];
  __shared__ u16 Bs[2][256 * 64];
  constexpr int NT = kD / 64;  // 16 K-tiles
  const int tid = threadIdx.x;
  const int wid = tid >> 6, lane = tid & 63;
  const int col = lane & 15, quad = lane >> 4;
  const int wm_ = wid >> 2, wn_ = wid & 3;

  // XCD-aware swizzle of flat block id (nwg % 8 == 0 for our shapes)
  const int nwg = gridDim.x * gridDim.y;
  int flat = blockIdx.y * gridDim.x + blockIdx.x;
  flat = (flat & 7) * (nwg >> 3) + (flat >> 3);
  const int n0 = (flat % gridDim.x) * 256;
  const int m0 = (flat / gridDim.x) * 256;

  const int srow = tid >> 3;                       // 0..63
  const int scol8 = (tid & 7) * 8;                 // storage chunk (elems)
  const int gch8 = ((tid & 7) ^ (srow & 7)) * 8;   // swizzled global chunk
  const u16* const Ag = A + (size_t)(m0 + srow) * lda + gch8;
  const u16* const Bg = BT + (size_t)(n0 + srow) * kD + gch8;

  f32x4 acc[8][4];
#pragma unroll
  for (int i = 0; i < 8; ++i)
#pragma unroll
    for (int j = 0; j < 4; ++j) acc[i][j] = (f32x4){0.f, 0.f, 0.f, 0.f};

#define STAGE_A(buf, rbase, k0)                                              \
  do {                                                                       \
    gload16(Ag + (size_t)(rbase)*lda + (k0),                                 \
            &As[buf][((rbase) + srow) * 64 + scol8]);                        \
    gload16(Ag + (size_t)((rbase) + 64) * lda + (k0),                        \
            &As[buf][((rbase) + 64 + srow) * 64 + scol8]);                   \
  } while (0)
#define STAGE_B(buf, rbase, k0)                                              \
  do {                                                                       \
    gload16(Bg + (size_t)(rbase)*kD + (k0),                                  \
            &Bs[buf][((rbase) + srow) * 64 + scol8]);                        \
    gload16(Bg + (size_t)((rbase) + 64) * kD + (k0),                         \
            &Bs[buf][((rbase) + 64 + srow) * 64 + scol8]);                   \
  } while (0)

  // prologue: tile0 complete + AT,BT of tile1 in flight
  STAGE_A(0, 0, 0);
  STAGE_B(0, 0, 0);
  STAGE_B(0, 128, 0);
  STAGE_A(0, 128, 0);
  STAGE_A(1, 0, 64);
  STAGE_B(1, 0, 64);
  asm volatile("s_waitcnt vmcnt(4)" ::: "memory");
  __builtin_amdgcn_s_barrier();

  int cur = 0;
  for (int t = 0; t < NT; ++t) {
    const int nxt = cur ^ 1;
#pragma unroll
    for (int ph = 0; ph < 4; ++ph) {
      const int mq = ph >> 1, nq = ph & 1;
      bf16x8 af[4][2], bv[2][2];
#pragma unroll
      for (int mi = 0; mi < 4; ++mi) {
        const int r = mq * 128 + wm_ * 64 + mi * 16 + col;
#pragma unroll
        for (int ks = 0; ks < 2; ++ks)
          af[mi][ks] = *(const bf16x8*)&As[cur][r * 64 +
                                               (((ks * 4 + quad) ^ (r & 7)) *
                                                8)];
      }
#pragma unroll
      for (int ni = 0; ni < 2; ++ni) {
        const int r = nq * 128 + wn_ * 32 + ni * 16 + col;
#pragma unroll
        for (int ks = 0; ks < 2; ++ks)
          bv[ni][ks] = *(const bf16x8*)&Bs[cur][r * 64 +
                                               (((ks * 4 + quad) ^ (r & 7)) *
                                                8)];
      }
      if (ph == 0) {
        if (t + 1 < NT) STAGE_B(nxt, 128, (t + 1) * 64);
      } else if (ph == 1) {
        if (t + 1 < NT) STAGE_A(nxt, 128, (t + 1) * 64);
      } else if (ph == 2) {
        if (t + 2 < NT) STAGE_A(cur, 0, (t + 2) * 64);
      } else {
        if (t + 2 < NT) STAGE_B(cur, 0, (t + 2) * 64);
      }
      __builtin_amdgcn_s_barrier();
      asm volatile("s_waitcnt lgkmcnt(0)" ::: "memory");
      __builtin_amdgcn_s_setprio(1);
#pragma unroll
      for (int mi = 0; mi < 4; ++mi)
#pragma unroll
        for (int ni = 0; ni < 2; ++ni)
#pragma unroll
          for (int ks = 0; ks < 2; ++ks)
            acc[mq * 4 + mi][nq * 2 + ni] =
                __builtin_amdgcn_mfma_f32_16x16x32_bf16(
                    af[mi][ks], bv[ni][ks], acc[mq * 4 + mi][nq * 2 + ni], 0,
                    0, 0);
      __builtin_amdgcn_s_setprio(0);
      if (ph == 3) {
        if (t + 2 < NT)
          asm volatile("s_waitcnt vmcnt(4)" ::: "memory");
        else if (t + 1 < NT)
          asm volatile("s_waitcnt vmcnt(0)" ::: "memory");
      }
      __builtin_amdgcn_s_barrier();
    }
    cur = nxt;
  }
#undef STAGE_A
#undef STAGE_B

  // epilogue: C row = m0 + mq*128 + wm_*64 + mi*16 + quad*4 + reg,
  //           col = n0 + nq*128 + wn_*32 + ni*16 + col
#pragma unroll
  for (int mig = 0; mig < 8; ++mig) {
    const int row =
        m0 + (mig >> 2) * 128 + wm_ * 64 + (mig & 3) * 16 + quad * 4;
#pragma unroll
    for (int reg = 0; reg < 4; ++reg) {
      u16* cp = C + (size_t)(row + reg) * ldc;
#pragma unroll
      for (int nig = 0; nig < 4; ++nig) {
        const int cc = n0 + (nig >> 1) * 128 + wn_ * 32 + (nig & 1) * 16 + col;
        cp[cc] = f2bf(acc[mig][nig][reg]);
      }
    }
  }
}

// C[m][n] = sum_k A[m][k] * BT[n][k]; A,BT bf16; K=1024. C fp32.
// 128x128 tile, BK=32, 4 waves x (4x4) 16x16x32 MFMAs (unchanged from R7).
template <bool F32OUT>
__global__ __launch_bounds__(256) void gemm_bt(const u16* __restrict__ A,
                                               const u16* __restrict__ BT,
                                               void* __restrict__ Cv, int lda,
                                               int ldc) {
  __shared__ u16 As[128 * 32];
  __shared__ u16 Bs[128 * 32];
  const int tid = threadIdx.x;
  const int w = tid >> 6, lane = tid & 63;
  const int col = lane & 15, quad = lane >> 4;
  const int wm = (w & 1) * 64, wn = (w >> 1) * 64;
  const int m0 = blockIdx.y * 128, n0 = blockIdx.x * 128;

  const int s0 = tid, s1 = 256 + tid;
  const int ar0 = s0 >> 2, ak0 = ((s0 & 3) ^ ((ar0 >> 1) & 3)) * 8;
  const int ar1 = s1 >> 2, ak1 = ((s1 & 3) ^ ((ar1 >> 1) & 3)) * 8;
  const u16* agp0 = A + (size_t)(m0 + ar0) * lda + ak0;
  const u16* agp1 = A + (size_t)(m0 + ar1) * lda + ak1;
  const u16* bgp0 = BT + (size_t)(n0 + ar0) * kD + ak0;
  const u16* bgp1 = BT + (size_t)(n0 + ar1) * kD + ak1;
  u16* al0 = &As[s0 * 8];
  u16* al1 = &As[s1 * 8];
  u16* bl0 = &Bs[s0 * 8];
  u16* bl1 = &Bs[s1 * 8];

  f32x4 acc[4][4];
#pragma unroll
  for (int mi = 0; mi < 4; ++mi)
#pragma unroll
    for (int ni = 0; ni < 4; ++ni) acc[mi][ni] = (f32x4){0.f, 0.f, 0.f, 0.f};

  for (int k0 = 0; k0 < kD; k0 += 32) {
    __syncthreads();
    gload16(agp0 + k0, al0);
    gload16(agp1 + k0, al1);
    gload16(bgp0 + k0, bl0);
    gload16(bgp1 + k0, bl1);
    __syncthreads();
    bf16x8 af[4], bfr[4];
#pragma unroll
    for (int mi = 0; mi < 4; ++mi) {
      const int r = wm + mi * 16 + col;
      af[mi] = *(const bf16x8*)&As[r * 32 + ((quad ^ ((r >> 1) & 3)) * 8)];
    }
#pragma unroll
    for (int ni = 0; ni < 4; ++ni) {
      const int r = wn + ni * 16 + col;
      bfr[ni] = *(const bf16x8*)&Bs[r * 32 + ((quad ^ ((r >> 1) & 3)) * 8)];
    }
#pragma unroll
    for (int mi = 0; mi < 4; ++mi)
#pragma unroll
      for (int ni = 0; ni < 4; ++ni)
        acc[mi][ni] = __builtin_amdgcn_mfma_f32_16x16x32_bf16(
            af[mi], bfr[ni], acc[mi][ni], 0, 0, 0);
  }

#pragma unroll
  for (int mi = 0; mi < 4; ++mi)
#pragma unroll
    for (int reg = 0; reg < 4; ++reg) {
      const int row = m0 + wm + mi * 16 + quad * 4 + reg;
#pragma unroll
      for (int ni = 0; ni < 4; ++ni) {
        const int cc = n0 + wn + ni * 16 + col;
        if (F32OUT)
          ((float*)Cv)[(size_t)row * ldc + cc] = acc[mi][ni][reg];
        else
          ((u16*)Cv)[(size_t)row * ldc + cc] = f2bf(acc[mi][ni][reg]);
      }
    }
}

// MFMA flash attention, transposed-S (unchanged from R11).
__global__ __launch_bounds__(256) void attn_fwd(u16* __restrict__ qkv) {
  __shared__ u16 Ks[2][64 * 64];  // dbuf; row-linear, 16B-chunk XOR-swizzled
  __shared__ u16 Vt[64][72];      // [dim][key]
  __shared__ u16 Ps[64][72];      // [q][key]
  const int tid = threadIdx.x;
  const int w = tid >> 6, lane = tid & 63;
  const int col = lane & 15, quad = lane >> 4;
  const int bh = blockIdx.x;
  const int b = bh >> 4, h = bh & 15;
  const int pa = blockIdx.y;  // 0..15
  const size_t base = (size_t)(b * kT) * kNq + h * 64;

  const int krr = lane >> 3;
  const int ksw = (lane & 7) ^ krr;
  const u16* const kgbase =
      qkv + base + kD + (size_t)(w * 16 + krr) * kNq + ksw * 8;

  const int vkp = (tid & 31) * 2, vd0 = (tid >> 5) * 8;  // V staging
  const u16* const vgbase = qkv + base + 2 * kD + (size_t)vkp * kNq + vd0;

  bf16x8 onesf;  // all-ones B-frag: row-sum MFMA for the softmax denominator
#pragma unroll
  for (int i = 0; i < 8; ++i) onesf[i] = (short)0x3F80;

  int cur = 0;
#pragma unroll
  for (int pass = 0; pass < 2; ++pass) {
    const int qt = pass ? (31 - pa) : pa;
    const int q0 = qt << 6;

    bf16x8 aq[2];
#pragma unroll
    for (int ks = 0; ks < 2; ++ks)
      aq[ks] = *(const bf16x8*)(qkv + base + (size_t)(q0 + w * 16 + col) * kNq +
                                ks * 32 + quad * 8);

    gload16(kgbase, &Ks[cur][(w * 16) * 64]);
    gload16(kgbase + (size_t)8 * kNq, &Ks[cur][(w * 16 + 8) * 64]);
    uint4 va = *(const uint4*)vgbase;
    uint4 vb = *(const uint4*)(vgbase + kNq);

    f32x4 o[4];  // O[q=w*16+quad*4+reg][d=nt*16+col]
#pragma unroll
    for (int nt = 0; nt < 4; ++nt) o[nt] = (f32x4){0.f, 0.f, 0.f, 0.f};
    f32x4 o4 = (f32x4){0.f, 0.f, 0.f, 0.f};  // l for q=w*16+quad*4+reg

    for (int kt = 0; kt <= qt; ++kt) {
      __syncthreads();  // drains K-DMA(kt)+V-loads(kt); prior tile reads done
      {  // write Vt(kt): v_perm_b32 packs key-pair words
        const unsigned int* aw = (const unsigned int*)&va;
        const unsigned int* bw = (const unsigned int*)&vb;
#pragma unroll
        for (int i = 0; i < 4; ++i) {
          *(unsigned int*)&Vt[vd0 + 2 * i][vkp] =
              __builtin_amdgcn_perm(bw[i], aw[i], 0x05040100u);
          *(unsigned int*)&Vt[vd0 + 2 * i + 1][vkp] =
              __builtin_amdgcn_perm(bw[i], aw[i], 0x07060302u);
        }
      }
      __syncthreads();  // Vt(kt) + Ks[cur] visible to all waves

      if (kt < qt) {  // prefetch kt+1; latency hides under QK/softmax/PV
        const size_t ko = (size_t)((kt + 1) << 6) * kNq;
        gload16(kgbase + ko, &Ks[cur ^ 1][(w * 16) * 64]);
        gload16(kgbase + ko + (size_t)8 * kNq, &Ks[cur ^ 1][(w * 16 + 8) * 64]);
        va = *(const uint4*)(vgbase + ko);
        vb = *(const uint4*)(vgbase + ko + kNq);
      }

      // St = K Q^T : rows = 64 keys (4 nt frags), cols = wave's 16 q
      f32x4 st[4];
#pragma unroll
      for (int nt = 0; nt < 4; ++nt) st[nt] = (f32x4){0.f, 0.f, 0.f, 0.f};
#pragma unroll
      for (int ks = 0; ks < 2; ++ks) {
#pragma unroll
        for (int nt = 0; nt < 4; ++nt) {
          const int kr = nt * 16 + col;  // key row
          const bf16x8 bk = *(const bf16x8*)&Ks[cur][kr * 64 +
                                                     (((ks * 4 + quad) ^
                                                       (col & 7)) *
                                                      8)];
          st[nt] = __builtin_amdgcn_mfma_f32_16x16x32_bf16(bk, aq[ks], st[nt],
                                                           0, 0, 0);
        }
      }

      // p = exp2(st) via raw hw exp2 (bounded logits); mask diagonal tile
      if (kt == qt) {
        const int qrel = w * 16 + col;
#pragma unroll
        for (int nt = 0; nt < 4; ++nt)
#pragma unroll
          for (int reg = 0; reg < 4; ++reg) {
            const int krel = nt * 16 + quad * 4 + reg;
            st[nt][reg] =
                (krel <= qrel) ? __builtin_amdgcn_exp2f(st[nt][reg]) : 0.f;
          }
      } else {
#pragma unroll
        for (int nt = 0; nt < 4; ++nt)
#pragma unroll
          for (int reg = 0; reg < 4; ++reg)
            st[nt][reg] = __builtin_amdgcn_exp2f(st[nt][reg]);
      }

      // P -> Ps[q][k]: per nt, 4 consecutive k -> one b64 write (cvt_pk pack)
#pragma unroll
      for (int nt = 0; nt < 4; ++nt) {
        uint2 pk;
        pk.x = cvtpk(st[nt][0], st[nt][1]);
        pk.y = cvtpk(st[nt][2], st[nt][3]);
        *(uint2*)&Ps[w * 16 + col][nt * 16 + quad * 4] = pk;
      }

      // O += P V; l += P 1 (same-wave Ps band roundtrip, no barrier needed)
#pragma unroll
      for (int ks = 0; ks < 2; ++ks) {
        const bf16x8 ap =
            *(const bf16x8*)&Ps[w * 16 + col][ks * 32 + quad * 8];
#pragma unroll
        for (int nt = 0; nt < 4; ++nt) {
          const bf16x8 bv =
              *(const bf16x8*)&Vt[nt * 16 + col][ks * 32 + quad * 8];
          o[nt] = __builtin_amdgcn_mfma_f32_16x16x32_bf16(ap, bv, o[nt], 0, 0,
                                                          0);
        }
        o4 = __builtin_amdgcn_mfma_f32_16x16x32_bf16(ap, onesf, o4, 0, 0, 0);
      }
      cur ^= 1;
    }

    // epilogue: o row q = w*16+quad*4+reg; l = o4[reg] (replicated over cols)
#pragma unroll
    for (int reg = 0; reg < 4; ++reg) {
      const float inv = 1.0f / o4[reg];
      u16* yp = qkv + base + (size_t)(q0 + w * 16 + quad * 4 + reg) * kNq;
#pragma unroll
      for (int nt = 0; nt < 4; ++nt)
        yp[nt * 16 + col] = f2bf(o[nt][reg] * inv);
    }
  }
}

extern "C" void kernel_launch(void* const* d_in, const int* in_sizes, int n_in,
                              void* d_out, int out_size, void* d_ws,
                              size_t ws_size, hipStream_t stream) {
  const float* x = (const float*)d_in[0];      // [8192][1024] fp32
  const float* w_qkv = (const float*)d_in[1];  // [1024][3072] fp32
  const float* w_out = (const float*)d_in[2];  // [1024][1024] fp32

  u16* wqkvT = (u16*)d_ws;                // [3072][1024] bf16  6.3MB
  u16* woutT = wqkvT + (size_t)kNq * kD;  // [1024][1024] bf16  2.1MB
  u16* qkvb = woutT + (size_t)kD * kD;    // [8192][3072] bf16 50.3MB
  u16* xb = (u16*)d_out;  // x as bf16 in d_out bytes (dead after qkv gemm)

  cvt_bf16<<<kM * kD / 2048, 256, 0, stream>>>(x, xb);
  transpose_bf<<<dim3(kNq / 32, kD / 32), 256, 0, stream>>>(w_qkv, wqkvT, kD,
                                                            kNq, kD);
  transpose_bf<<<dim3(kD / 32, kD / 32), 256, 0, stream>>>(w_out, woutT, kD,
                                                           kD, 0);
  gemm256<<<dim3(kNq / 256, kM / 256), 512, 0, stream>>>(xb, wqkvT, qkvb, kD,
                                                         kNq);
  attn_fwd<<<dim3(kB * kH, 16), 256, 0, stream>>>(qkvb);
  gemm_bt<true><<<dim3(kD / 128, kM / 128), 256, 0, stream>>>(qkvb, woutT,
                                                              d_out, kNq, kD);
}

// Round 4
// 248.754 us; speedup vs baseline: 1.0345x; 1.0345x over previous
//
#include <hip/hip_runtime.h>
#include <hip/hip_bf16.h>

// CausalSelfAttention: B=4, T=2048, D=1024, H=16, DH=64.
// Dtypes (established): inputs fp32, output fp32 (absmax thresh 0.075).
// R13: gemm256 LDS-read diet (R12 was LDS-throughput-bound: 48 ds_read_b128
// per wave per K-tile = 2.5:1 LDS:MFMA cycles -> 25% MfmaUtil).
//  - Fragments read ONCE per K-tile, held in regs across the 2 phases using
//    them: ph0 reads af0+bv0 (12), ph1 reads bv1 (4), ph2 reads af1 (8),
//    ph3 reads nothing. 24 reads/wave/K-tile (half of R12).
//  - m201-style staging: one half-tile per phase, each slot staged exactly
//    one phase after its last read; single counted vmcnt(6) per K-tile
//    (3 half-tiles in flight, 4-7 phases of prefetch cover). Never vmcnt(0)
//    mid-loop.
// K-accumulation order identical to R12 -> qkvb bit-identical.
// gemm2 (128^2 gemm_bt) + attn unchanged from R12.

namespace {
constexpr int kB = 4, kT = 2048, kD = 1024, kH = 16;
constexpr int kM = kB * kT;  // 8192
constexpr int kNq = 3 * kD;  // 3072
constexpr float kS = 0.180336880f;  // log2(e)/sqrt(64), folded into Q weights
}  // namespace

typedef unsigned short u16;
typedef short bf16x8 __attribute__((ext_vector_type(8)));  // 8 bf16, 4 VGPR
typedef float f32x4 __attribute__((ext_vector_type(4)));

__device__ __forceinline__ u16 f2bf(float f) {
  unsigned int u = __float_as_uint(f);
  u += 0x7fffu + ((u >> 16) & 1u);  // round-to-nearest-even
  return (u16)(u >> 16);
}
__device__ __forceinline__ unsigned int pack2(float a, float b) {
  return (unsigned int)f2bf(a) | ((unsigned int)f2bf(b) << 16);
}
// packed f32x2 -> bf16x2 in one VALU op (RNE)
__device__ __forceinline__ unsigned int cvtpk(float a, float b) {
  unsigned int r;
  asm("v_cvt_pk_bf16_f32 %0, %1, %2" : "=v"(r) : "v"(a), "v"(b));
  return r;
}

// async 16B global -> LDS (wave-uniform base + lane*16 semantics)
__device__ __forceinline__ void gload16(const u16* g, u16* l) {
  __builtin_amdgcn_global_load_lds(
      (const __attribute__((address_space(1))) unsigned int*)(uintptr_t)g,
      (__attribute__((address_space(3))) unsigned int*)(uintptr_t)l, 16, 0, 0);
}

// x fp32 -> bf16, 8 elems/thread
__global__ __launch_bounds__(256) void cvt_bf16(const float* __restrict__ x,
                                                u16* __restrict__ xb) {
  const size_t i = ((size_t)blockIdx.x * 256 + threadIdx.x) * 8;
  const float4 v0 = *(const float4*)(x + i);
  const float4 v1 = *(const float4*)(x + i + 4);
  uint4 p;
  p.x = pack2(v0.x, v0.y);
  p.y = pack2(v0.z, v0.w);
  p.z = pack2(v1.x, v1.y);
  p.w = pack2(v1.z, v1.w);
  *(uint4*)(xb + i) = p;
}

// WT[n][k] = bf16(W[k][n] * (n < nscale ? kS : 1)); W fp32 [K][N].
// 32x32 tiles via LDS. nscale folds the softmax scale into Q-columns free.
__global__ __launch_bounds__(256) void transpose_bf(const float* __restrict__ W,
                                                    u16* __restrict__ WT,
                                                    int K, int N, int nscale) {
  __shared__ float T[32][33];
  const int tid = threadIdx.x;
  const int nb = blockIdx.x * 32, kb = blockIdx.y * 32;
  const int r = tid >> 3, c = (tid & 7) * 4;
  const float4 v = *(const float4*)&W[(size_t)(kb + r) * N + nb + c];
  T[r][c + 0] = v.x;
  T[r][c + 1] = v.y;
  T[r][c + 2] = v.z;
  T[r][c + 3] = v.w;
  __syncthreads();
  const float s = (nb + r < nscale) ? kS : 1.0f;
  uint2 p;
  p.x = pack2(T[c + 0][r] * s, T[c + 1][r] * s);
  p.y = pack2(T[c + 2][r] * s, T[c + 3][r] * s);
  *(uint2*)&WT[(size_t)(nb + r) * K + kb + c] = p;
}

// gemm256 helpers: fragment reads (once per K-tile) + MFMA quadrant.
__device__ __forceinline__ void read_afrag(bf16x8 (&AF)[4][2], const u16* Asb,
                                           int half, int wm_, int col,
                                           int quad) {
#pragma unroll
  for (int mi = 0; mi < 4; ++mi) {
    const int r = half * 128 + wm_ * 64 + mi * 16 + col;
#pragma unroll
    for (int ks = 0; ks < 2; ++ks)
      AF[mi][ks] =
          *(const bf16x8*)&Asb[r * 64 + (((ks * 4 + quad) ^ (r & 7)) * 8)];
  }
}
__device__ __forceinline__ void read_bfrag(bf16x8 (&BV)[2][2], const u16* Bsb,
                                           int half, int wn_, int col,
                                           int quad) {
#pragma unroll
  for (int ni = 0; ni < 2; ++ni) {
    const int r = half * 128 + wn_ * 32 + ni * 16 + col;
#pragma unroll
    for (int ks = 0; ks < 2; ++ks)
      BV[ni][ks] =
          *(const bf16x8*)&Bsb[r * 64 + (((ks * 4 + quad) ^ (r & 7)) * 8)];
  }
}
template <int MQ, int NQ>
__device__ __forceinline__ void mfma_quad(f32x4 (&acc)[8][4],
                                          const bf16x8 (&AF)[4][2],
                                          const bf16x8 (&BV)[2][2]) {
#pragma unroll
  for (int mi = 0; mi < 4; ++mi)
#pragma unroll
    for (int ni = 0; ni < 2; ++ni)
#pragma unroll
      for (int ks = 0; ks < 2; ++ks)
        acc[MQ * 4 + mi][NQ * 2 + ni] =
            __builtin_amdgcn_mfma_f32_16x16x32_bf16(
                AF[mi][ks], BV[ni][ks], acc[MQ * 4 + mi][NQ * 2 + ni], 0, 0,
                0);
}

// ---------------------------------------------------------------------------
// 256x256 8-phase GEMM: C[m][n] = sum_k A[m][k] * BT[n][k]; bf16 in, bf16 out.
// K=1024 (16 K-tiles of BK=64). 8 waves 2(M)x4(N); wave output 128x64
// (interleaved halves). Per K-tile 4 quadrant-phases; fragments register-held.
// Staging (one 128-row half-tile per phase, slot staged 1 phase after its
// last read): ph0: BH0(t+1)->nxt, ph1: AH0(t+2)->cur, ph2: BH1(t+2)->cur,
// ph3: AH1(t+2)->cur, then vmcnt(6) (leaves the 3 t+2 halves in flight).
// Prologue: AH0,BH0,BH1,AH1(0), AH0,BH1,AH1(1) -> vmcnt(6).
// ---------------------------------------------------------------------------
__global__ __launch_bounds__(512, 2) void gemm256(const u16* __restrict__ A,
                                                  const u16* __restrict__ BT,
                                                  u16* __restrict__ C, int lda,
                                                  int ldc) {
  __shared__ u16 As[2][256 * 64];
  __shared__ u16 Bs[2][256 * 64];
  constexpr int NT = kD / 64;  // 16 K-tiles
  const int tid = threadIdx.x;
  const int wid = tid >> 6, lane = tid & 63;
  const int col = lane & 15, quad = lane >> 4;
  const int wm_ = wid >> 2, wn_ = wid & 3;

  // XCD-aware swizzle of flat block id (nwg % 8 == 0 here: 384)
  const int nwg = gridDim.x * gridDim.y;
  int flat = blockIdx.y * gridDim.x + blockIdx.x;
  flat = (flat & 7) * (nwg >> 3) + (flat >> 3);
  const int n0 = (flat % gridDim.x) * 256;
  const int m0 = (flat / gridDim.x) * 256;

  const int srow = tid >> 3;                      // 0..63
  const int scol8 = (tid & 7) * 8;                // storage chunk (elems)
  const int gch8 = ((tid & 7) ^ (srow & 7)) * 8;  // swizzled global chunk
  const u16* const Ag = A + (size_t)(m0 + srow) * lda + gch8;
  const u16* const Bg = BT + (size_t)(n0 + srow) * kD + gch8;

  f32x4 acc[8][4];
#pragma unroll
  for (int i = 0; i < 8; ++i)
#pragma unroll
    for (int j = 0; j < 4; ++j) acc[i][j] = (f32x4){0.f, 0.f, 0.f, 0.f};

  // STAGE_X(buf, half, k0): stage one 128-row half-tile (2 gload16/thread)
#define STAGE_A(buf, half, k0)                                           \
  do {                                                                   \
    gload16(Ag + (size_t)((half)*128) * lda + (k0),                      \
            &As[buf][((half)*128 + srow) * 64 + scol8]);                 \
    gload16(Ag + (size_t)((half)*128 + 64) * lda + (k0),                 \
            &As[buf][((half)*128 + 64 + srow) * 64 + scol8]);            \
  } while (0)
#define STAGE_B(buf, half, k0)                                           \
  do {                                                                   \
    gload16(Bg + (size_t)((half)*128) * kD + (k0),                       \
            &Bs[buf][((half)*128 + srow) * 64 + scol8]);                 \
    gload16(Bg + (size_t)((half)*128 + 64) * kD + (k0),                  \
            &Bs[buf][((half)*128 + 64 + srow) * 64 + scol8]);            \
  } while (0)

  // prologue: tile0 complete + AH0,BH1,AH1 of tile1 in flight (3 units)
  STAGE_A(0, 0, 0);
  STAGE_B(0, 0, 0);
  STAGE_B(0, 1, 0);
  STAGE_A(0, 1, 0);
  STAGE_A(1, 0, 64);
  STAGE_B(1, 1, 64);
  STAGE_A(1, 1, 64);
  asm volatile("s_waitcnt vmcnt(6)" ::: "memory");
  __builtin_amdgcn_s_barrier();

  for (int t = 0; t < NT; ++t) {
    const int cur = t & 1;
    const u16* Ac = &As[cur][0];
    const u16* Bc = &Bs[cur][0];
    const int k2 = (t + 2) * 64;
    bf16x8 af0[4][2], af1[4][2], bv0[2][2], bv1[2][2];

    // ph0: quad(0,0); read af0(8)+bv0(4); stage BH0(t+1)->nxt
    read_afrag(af0, Ac, 0, wm_, col, quad);
    read_bfrag(bv0, Bc, 0, wn_, col, quad);
    if (t + 1 < NT) STAGE_B(cur ^ 1, 0, (t + 1) * 64);
    __builtin_amdgcn_s_barrier();
    asm volatile("s_waitcnt lgkmcnt(0)" ::: "memory");
    __builtin_amdgcn_s_setprio(1);
    mfma_quad<0, 0>(acc, af0, bv0);
    __builtin_amdgcn_s_setprio(0);
    __builtin_amdgcn_s_barrier();

    // ph1: quad(0,1); read bv1(4); stage AH0(t+2)->cur (AH0 free after ph0)
    read_bfrag(bv1, Bc, 1, wn_, col, quad);
    if (t + 2 < NT) STAGE_A(cur, 0, k2);
    __builtin_amdgcn_s_barrier();
    asm volatile("s_waitcnt lgkmcnt(0)" ::: "memory");
    __builtin_amdgcn_s_setprio(1);
    mfma_quad<0, 1>(acc, af0, bv1);
    __builtin_amdgcn_s_setprio(0);
    __builtin_amdgcn_s_barrier();

    // ph2: quad(1,0); read af1(8); stage BH1(t+2)->cur (BH1 free after ph1)
    read_afrag(af1, Ac, 1, wm_, col, quad);
    if (t + 2 < NT) STAGE_B(cur, 1, k2);
    __builtin_amdgcn_s_barrier();
    asm volatile("s_waitcnt lgkmcnt(0)" ::: "memory");
    __builtin_amdgcn_s_setprio(1);
    mfma_quad<1, 0>(acc, af1, bv0);
    __builtin_amdgcn_s_setprio(0);
    __builtin_amdgcn_s_barrier();

    // ph3: quad(1,1); no reads; stage AH1(t+2)->cur (AH1 free after ph2)
    if (t + 2 < NT) STAGE_A(cur, 1, k2);
    __builtin_amdgcn_s_barrier();
    __builtin_amdgcn_s_setprio(1);
    mfma_quad<1, 1>(acc, af1, bv1);
    __builtin_amdgcn_s_setprio(0);
    if (t + 2 < NT)
      asm volatile("s_waitcnt vmcnt(6)" ::: "memory");
    else if (t + 1 < NT)
      asm volatile("s_waitcnt vmcnt(0)" ::: "memory");
    __builtin_amdgcn_s_barrier();
  }
#undef STAGE_A
#undef STAGE_B

  // epilogue: C row = m0 + mq*128 + wm_*64 + mi*16 + quad*4 + reg,
  //           col = n0 + nq*128 + wn_*32 + ni*16 + col
#pragma unroll
  for (int mig = 0; mig < 8; ++mig) {
    const int row =
        m0 + (mig >> 2) * 128 + wm_ * 64 + (mig & 3) * 16 + quad * 4;
#pragma unroll
    for (int reg = 0; reg < 4; ++reg) {
      u16* cp = C + (size_t)(row + reg) * ldc;
#pragma unroll
      for (int nig = 0; nig < 4; ++nig) {
        const int cc = n0 + (nig >> 1) * 128 + wn_ * 32 + (nig & 1) * 16 + col;
        cp[cc] = f2bf(acc[mig][nig][reg]);
      }
    }
  }
}

// C[m][n] = sum_k A[m][k] * BT[n][k]; A,BT bf16; K=1024. C fp32.
// 128x128 tile, BK=32, 4 waves x (4x4) 16x16x32 MFMAs (unchanged from R7).
template <bool F32OUT>
__global__ __launch_bounds__(256) void gemm_bt(const u16* __restrict__ A,
                                               const u16* __restrict__ BT,
                                               void* __restrict__ Cv, int lda,
                                               int ldc) {
  __shared__ u16 As[128 * 32];
  __shared__ u16 Bs[128 * 32];
  const int tid = threadIdx.x;
  const int w = tid >> 6, lane = tid & 63;
  const int col = lane & 15, quad = lane >> 4;
  const int wm = (w & 1) * 64, wn = (w >> 1) * 64;
  const int m0 = blockIdx.y * 128, n0 = blockIdx.x * 128;

  const int s0 = tid, s1 = 256 + tid;
  const int ar0 = s0 >> 2, ak0 = ((s0 & 3) ^ ((ar0 >> 1) & 3)) * 8;
  const int ar1 = s1 >> 2, ak1 = ((s1 & 3) ^ ((ar1 >> 1) & 3)) * 8;
  const u16* agp0 = A + (size_t)(m0 + ar0) * lda + ak0;
  const u16* agp1 = A + (size_t)(m0 + ar1) * lda + ak1;
  const u16* bgp0 = BT + (size_t)(n0 + ar0) * kD + ak0;
  const u16* bgp1 = BT + (size_t)(n0 + ar1) * kD + ak1;
  u16* al0 = &As[s0 * 8];
  u16* al1 = &As[s1 * 8];
  u16* bl0 = &Bs[s0 * 8];
  u16* bl1 = &Bs[s1 * 8];

  f32x4 acc[4][4];
#pragma unroll
  for (int mi = 0; mi < 4; ++mi)
#pragma unroll
    for (int ni = 0; ni < 4; ++ni) acc[mi][ni] = (f32x4){0.f, 0.f, 0.f, 0.f};

  for (int k0 = 0; k0 < kD; k0 += 32) {
    __syncthreads();
    gload16(agp0 + k0, al0);
    gload16(agp1 + k0, al1);
    gload16(bgp0 + k0, bl0);
    gload16(bgp1 + k0, bl1);
    __syncthreads();
    bf16x8 af[4], bfr[4];
#pragma unroll
    for (int mi = 0; mi < 4; ++mi) {
      const int r = wm + mi * 16 + col;
      af[mi] = *(const bf16x8*)&As[r * 32 + ((quad ^ ((r >> 1) & 3)) * 8)];
    }
#pragma unroll
    for (int ni = 0; ni < 4; ++ni) {
      const int r = wn + ni * 16 + col;
      bfr[ni] = *(const bf16x8*)&Bs[r * 32 + ((quad ^ ((r >> 1) & 3)) * 8)];
    }
#pragma unroll
    for (int mi = 0; mi < 4; ++mi)
#pragma unroll
      for (int ni = 0; ni < 4; ++ni)
        acc[mi][ni] = __builtin_amdgcn_mfma_f32_16x16x32_bf16(
            af[mi], bfr[ni], acc[mi][ni], 0, 0, 0);
  }

#pragma unroll
  for (int mi = 0; mi < 4; ++mi)
#pragma unroll
    for (int reg = 0; reg < 4; ++reg) {
      const int row = m0 + wm + mi * 16 + quad * 4 + reg;
#pragma unroll
      for (int ni = 0; ni < 4; ++ni) {
        const int cc = n0 + wn + ni * 16 + col;
        if (F32OUT)
          ((float*)Cv)[(size_t)row * ldc + cc] = acc[mi][ni][reg];
        else
          ((u16*)Cv)[(size_t)row * ldc + cc] = f2bf(acc[mi][ni][reg]);
      }
    }
}

// MFMA flash attention, transposed-S (unchanged from R11).
__global__ __launch_bounds__(256) void attn_fwd(u16* __restrict__ qkv) {
  __shared__ u16 Ks[2][64 * 64];  // dbuf; row-linear, 16B-chunk XOR-swizzled
  __shared__ u16 Vt[64][72];      // [dim][key]
  __shared__ u16 Ps[64][72];      // [q][key]
  const int tid = threadIdx.x;
  const int w = tid >> 6, lane = tid & 63;
  const int col = lane & 15, quad = lane >> 4;
  const int bh = blockIdx.x;
  const int b = bh >> 4, h = bh & 15;
  const int pa = blockIdx.y;  // 0..15
  const size_t base = (size_t)(b * kT) * kNq + h * 64;

  const int krr = lane >> 3;
  const int ksw = (lane & 7) ^ krr;
  const u16* const kgbase =
      qkv + base + kD + (size_t)(w * 16 + krr) * kNq + ksw * 8;

  const int vkp = (tid & 31) * 2, vd0 = (tid >> 5) * 8;  // V staging
  const u16* const vgbase = qkv + base + 2 * kD + (size_t)vkp * kNq + vd0;

  bf16x8 onesf;  // all-ones B-frag: row-sum MFMA for the softmax denominator
#pragma unroll
  for (int i = 0; i < 8; ++i) onesf[i] = (short)0x3F80;

  int cur = 0;
#pragma unroll
  for (int pass = 0; pass < 2; ++pass) {
    const int qt = pass ? (31 - pa) : pa;
    const int q0 = qt << 6;

    bf16x8 aq[2];
#pragma unroll
    for (int ks = 0; ks < 2; ++ks)
      aq[ks] = *(const bf16x8*)(qkv + base + (size_t)(q0 + w * 16 + col) * kNq +
                                ks * 32 + quad * 8);

    gload16(kgbase, &Ks[cur][(w * 16) * 64]);
    gload16(kgbase + (size_t)8 * kNq, &Ks[cur][(w * 16 + 8) * 64]);
    uint4 va = *(const uint4*)vgbase;
    uint4 vb = *(const uint4*)(vgbase + kNq);

    f32x4 o[4];  // O[q=w*16+quad*4+reg][d=nt*16+col]
#pragma unroll
    for (int nt = 0; nt < 4; ++nt) o[nt] = (f32x4){0.f, 0.f, 0.f, 0.f};
    f32x4 o4 = (f32x4){0.f, 0.f, 0.f, 0.f};  // l for q=w*16+quad*4+reg

    for (int kt = 0; kt <= qt; ++kt) {
      __syncthreads();  // drains K-DMA(kt)+V-loads(kt); prior tile reads done
      {  // write Vt(kt): v_perm_b32 packs key-pair words
        const unsigned int* aw = (const unsigned int*)&va;
        const unsigned int* bw = (const unsigned int*)&vb;
#pragma unroll
        for (int i = 0; i < 4; ++i) {
          *(unsigned int*)&Vt[vd0 + 2 * i][vkp] =
              __builtin_amdgcn_perm(bw[i], aw[i], 0x05040100u);
          *(unsigned int*)&Vt[vd0 + 2 * i + 1][vkp] =
              __builtin_amdgcn_perm(bw[i], aw[i], 0x07060302u);
        }
      }
      __syncthreads();  // Vt(kt) + Ks[cur] visible to all waves

      if (kt < qt) {  // prefetch kt+1; latency hides under QK/softmax/PV
        const size_t ko = (size_t)((kt + 1) << 6) * kNq;
        gload16(kgbase + ko, &Ks[cur ^ 1][(w * 16) * 64]);
        gload16(kgbase + ko + (size_t)8 * kNq, &Ks[cur ^ 1][(w * 16 + 8) * 64]);
        va = *(const uint4*)(vgbase + ko);
        vb = *(const uint4*)(vgbase + ko + kNq);
      }

      // St = K Q^T : rows = 64 keys (4 nt frags), cols = wave's 16 q
      f32x4 st[4];
#pragma unroll
      for (int nt = 0; nt < 4; ++nt) st[nt] = (f32x4){0.f, 0.f, 0.f, 0.f};
#pragma unroll
      for (int ks = 0; ks < 2; ++ks) {
#pragma unroll
        for (int nt = 0; nt < 4; ++nt) {
          const int kr = nt * 16 + col;  // key row
          const bf16x8 bk = *(const bf16x8*)&Ks[cur][kr * 64 +
                                                     (((ks * 4 + quad) ^
                                                       (col & 7)) *
                                                      8)];
          st[nt] = __builtin_amdgcn_mfma_f32_16x16x32_bf16(bk, aq[ks], st[nt],
                                                           0, 0, 0);
        }
      }

      // p = exp2(st) via raw hw exp2 (bounded logits); mask diagonal tile
      if (kt == qt) {
        const int qrel = w * 16 + col;
#pragma unroll
        for (int nt = 0; nt < 4; ++nt)
#pragma unroll
          for (int reg = 0; reg < 4; ++reg) {
            const int krel = nt * 16 + quad * 4 + reg;
            st[nt][reg] =
                (krel <= qrel) ? __builtin_amdgcn_exp2f(st[nt][reg]) : 0.f;
          }
      } else {
#pragma unroll
        for (int nt = 0; nt < 4; ++nt)
#pragma unroll
          for (int reg = 0; reg < 4; ++reg)
            st[nt][reg] = __builtin_amdgcn_exp2f(st[nt][reg]);
      }

      // P -> Ps[q][k]: per nt, 4 consecutive k -> one b64 write (cvt_pk pack)
#pragma unroll
      for (int nt = 0; nt < 4; ++nt) {
        uint2 pk;
        pk.x = cvtpk(st[nt][0], st[nt][1]);
        pk.y = cvtpk(st[nt][2], st[nt][3]);
        *(uint2*)&Ps[w * 16 + col][nt * 16 + quad * 4] = pk;
      }

      // O += P V; l += P 1 (same-wave Ps band roundtrip, no barrier needed)
#pragma unroll
      for (int ks = 0; ks < 2; ++ks) {
        const bf16x8 ap =
            *(const bf16x8*)&Ps[w * 16 + col][ks * 32 + quad * 8];
#pragma unroll
        for (int nt = 0; nt < 4; ++nt) {
          const bf16x8 bv =
              *(const bf16x8*)&Vt[nt * 16 + col][ks * 32 + quad * 8];
          o[nt] = __builtin_amdgcn_mfma_f32_16x16x32_bf16(ap, bv, o[nt], 0, 0,
                                                          0);
        }
        o4 = __builtin_amdgcn_mfma_f32_16x16x32_bf16(ap, onesf, o4, 0, 0, 0);
      }
      cur ^= 1;
    }

    // epilogue: o row q = w*16+quad*4+reg; l = o4[reg] (replicated over cols)
#pragma unroll
    for (int reg = 0; reg < 4; ++reg) {
      const float inv = 1.0f / o4[reg];
      u16* yp = qkv + base + (size_t)(q0 + w * 16 + quad * 4 + reg) * kNq;
#pragma unroll
      for (int nt = 0; nt < 4; ++nt)
        yp[nt * 16 + col] = f2bf(o[nt][reg] * inv);
    }
  }
}

extern "C" void kernel_launch(void* const* d_in, const int* in_sizes, int n_in,
                              void* d_out, int out_size, void* d_ws,
                              size_t ws_size, hipStream_t stream) {
  const float* x = (const float*)d_in[0];      // [8192][1024] fp32
  const float* w_qkv = (const float*)d_in[1];  // [1024][3072] fp32
  const float* w_out = (const float*)d_in[2];  // [1024][1024] fp32

  u16* wqkvT = (u16*)d_ws;                // [3072][1024] bf16  6.3MB
  u16* woutT = wqkvT + (size_t)kNq * kD;  // [1024][1024] bf16  2.1MB
  u16* qkvb = woutT + (size_t)kD * kD;    // [8192][3072] bf16 50.3MB
  u16* xb = (u16*)d_out;  // x as bf16 in d_out bytes (dead after qkv gemm)

  cvt_bf16<<<kM * kD / 2048, 256, 0, stream>>>(x, xb);
  transpose_bf<<<dim3(kNq / 32, kD / 32), 256, 0, stream>>>(w_qkv, wqkvT, kD,
                                                            kNq, kD);
  transpose_bf<<<dim3(kD / 32, kD / 32), 256, 0, stream>>>(w_out, woutT, kD,
                                                           kD, 0);
  gemm256<<<dim3(kNq / 256, kM / 256), 512, 0, stream>>>(xb, wqkvT, qkvb, kD,
                                                         kNq);
  attn_fwd<<<dim3(kB * kH, 16), 256, 0, stream>>>(qkvb);
  gemm_bt<true><<<dim3(kD / 128, kM / 128), 256, 0, stream>>>(qkvb, woutT,
                                                              d_out, kNq, kD);
}

// Round 5
// 246.995 us; speedup vs baseline: 1.0419x; 1.0071x over previous
//
#include <hip/hip_runtime.h>
#include <hip/hip_bf16.h>

// CausalSelfAttention: B=4, T=2048, D=1024, H=16, DH=64.
// Dtypes (established): inputs fp32, output fp32 (absmax thresh 0.075).
// R14: GEMM tiling fixed for occupancy rounds. R13's 256x256 grid was 384
// blocks at 1 block/CU = 1.5 rounds -> 25% idle tail. New 256(M)x128(N)
// tile, 96KB LDS, 8 waves (2M x 4N, wave tile 128x32):
//   gemm1: 24x32 = 768 blocks = 3 clean rounds
//   gemm2: 8x32  = 256 blocks = 1 clean round (replaces 128^2 gemm_bt)
// 2 phases per K-tile (M-halves), 16 MFMA/phase; reads ph0=12, ph1=8 b128;
// stage AH1(t+1)@ph0, AH0+B(t+2)@ph1; counted vmcnt(6) at each phase end
// (never 0 mid-loop). Accumulation order unchanged -> bit-identical sums.
// attn unchanged from R11.

namespace {
constexpr int kB = 4, kT = 2048, kD = 1024, kH = 16;
constexpr int kM = kB * kT;  // 8192
constexpr int kNq = 3 * kD;  // 3072
constexpr float kS = 0.180336880f;  // log2(e)/sqrt(64), folded into Q weights
}  // namespace

typedef unsigned short u16;
typedef short bf16x8 __attribute__((ext_vector_type(8)));  // 8 bf16, 4 VGPR
typedef float f32x4 __attribute__((ext_vector_type(4)));

__device__ __forceinline__ u16 f2bf(float f) {
  unsigned int u = __float_as_uint(f);
  u += 0x7fffu + ((u >> 16) & 1u);  // round-to-nearest-even
  return (u16)(u >> 16);
}
__device__ __forceinline__ unsigned int pack2(float a, float b) {
  return (unsigned int)f2bf(a) | ((unsigned int)f2bf(b) << 16);
}
// packed f32x2 -> bf16x2 in one VALU op (RNE)
__device__ __forceinline__ unsigned int cvtpk(float a, float b) {
  unsigned int r;
  asm("v_cvt_pk_bf16_f32 %0, %1, %2" : "=v"(r) : "v"(a), "v"(b));
  return r;
}

// async 16B global -> LDS (wave-uniform base + lane*16 semantics)
__device__ __forceinline__ void gload16(const u16* g, u16* l) {
  __builtin_amdgcn_global_load_lds(
      (const __attribute__((address_space(1))) unsigned int*)(uintptr_t)g,
      (__attribute__((address_space(3))) unsigned int*)(uintptr_t)l, 16, 0, 0);
}

// x fp32 -> bf16, 8 elems/thread
__global__ __launch_bounds__(256) void cvt_bf16(const float* __restrict__ x,
                                                u16* __restrict__ xb) {
  const size_t i = ((size_t)blockIdx.x * 256 + threadIdx.x) * 8;
  const float4 v0 = *(const float4*)(x + i);
  const float4 v1 = *(const float4*)(x + i + 4);
  uint4 p;
  p.x = pack2(v0.x, v0.y);
  p.y = pack2(v0.z, v0.w);
  p.z = pack2(v1.x, v1.y);
  p.w = pack2(v1.z, v1.w);
  *(uint4*)(xb + i) = p;
}

// WT[n][k] = bf16(W[k][n] * (n < nscale ? kS : 1)); W fp32 [K][N].
// 32x32 tiles via LDS. nscale folds the softmax scale into Q-columns free.
__global__ __launch_bounds__(256) void transpose_bf(const float* __restrict__ W,
                                                    u16* __restrict__ WT,
                                                    int K, int N, int nscale) {
  __shared__ float T[32][33];
  const int tid = threadIdx.x;
  const int nb = blockIdx.x * 32, kb = blockIdx.y * 32;
  const int r = tid >> 3, c = (tid & 7) * 4;
  const float4 v = *(const float4*)&W[(size_t)(kb + r) * N + nb + c];
  T[r][c + 0] = v.x;
  T[r][c + 1] = v.y;
  T[r][c + 2] = v.z;
  T[r][c + 3] = v.w;
  __syncthreads();
  const float s = (nb + r < nscale) ? kS : 1.0f;
  uint2 p;
  p.x = pack2(T[c + 0][r] * s, T[c + 1][r] * s);
  p.y = pack2(T[c + 2][r] * s, T[c + 3][r] * s);
  *(uint2*)&WT[(size_t)(nb + r) * K + kb + c] = p;
}

// ---------------------------------------------------------------------------
// 256(M)x128(N) 8-wave GEMM: C[m][n] = sum_k A[m][k]*BT[n][k]; bf16 in,
// bf16/f32 out. K=1024 = 16 K-tiles of BK=64. LDS 96KB (A 2x256x64,
// B 2x128x64). Waves 2(M)x4(N); wave tile 128 rows (64 per M-half,
// interleaved) x 32 cols. Per K-tile 2 phases (M-halves):
//   ph0: read AH0-frags(8)+B-frags(4); stage AH1(t+1)->nxt [2 loads]
//   ph1: read AH1-frags(8);            stage AH0(t+2),B(t+2)->cur [4 loads]
// vmcnt(6) at each phase end: forces this-phase+1 data complete while
// leaving 6 newest loads in flight (ledger verified; every slot restaged
// exactly one phase after its last read). Never vmcnt(0) mid-loop.
// XOR-granule swizzle on 16B chunks: storage chunk c of row r holds global
// chunk c^(r&7) -> ds_read_b128 at 128B stride conflict-free (R12: 0).
// ---------------------------------------------------------------------------
template <bool F32OUT>
__global__ __launch_bounds__(512, 2) void gemm_mt(const u16* __restrict__ A,
                                                  const u16* __restrict__ BT,
                                                  void* __restrict__ Cv,
                                                  int lda, int ldc) {
  __shared__ u16 As[2][256 * 64];
  __shared__ u16 Bs[2][128 * 64];
  constexpr int NT = kD / 64;  // 16 K-tiles
  const int tid = threadIdx.x;
  const int wid = tid >> 6, lane = tid & 63;
  const int col = lane & 15, quad = lane >> 4;
  const int wm_ = wid >> 2, wn_ = wid & 3;

  // XCD-aware swizzle of flat block id (nwg % 8 == 0: 768 / 256)
  const int nwg = gridDim.x * gridDim.y;
  int flat = blockIdx.y * gridDim.x + blockIdx.x;
  flat = (flat & 7) * (nwg >> 3) + (flat >> 3);
  const int n0 = (flat % gridDim.x) * 128;
  const int m0 = (flat / gridDim.x) * 256;

  const int srow = tid >> 3;                      // 0..63
  const int scol8 = (tid & 7) * 8;                // storage chunk (elems)
  const int gch8 = ((tid & 7) ^ (srow & 7)) * 8;  // swizzled global chunk
  const u16* const Ag = A + (size_t)(m0 + srow) * lda + gch8;
  const u16* const Bg = BT + (size_t)(n0 + srow) * kD + gch8;

  f32x4 acc[8][2];
#pragma unroll
  for (int i = 0; i < 8; ++i)
#pragma unroll
    for (int j = 0; j < 2; ++j) acc[i][j] = (f32x4){0.f, 0.f, 0.f, 0.f};

  // STAGE_AH: one 128-row A half (2 gload16/thread); STAGE_BF: B tile (2).
#define STAGE_AH(buf, half, k0)                                      \
  do {                                                               \
    gload16(Ag + (size_t)((half)*128) * lda + (k0),                  \
            &As[buf][((half)*128 + srow) * 64 + scol8]);             \
    gload16(Ag + (size_t)((half)*128 + 64) * lda + (k0),             \
            &As[buf][((half)*128 + 64 + srow) * 64 + scol8]);        \
  } while (0)
#define STAGE_BF(buf, k0)                                            \
  do {                                                               \
    gload16(Bg + (size_t)(k0), &Bs[buf][srow * 64 + scol8]);         \
    gload16(Bg + (size_t)64 * kD + (k0),                             \
            &Bs[buf][(64 + srow) * 64 + scol8]);                     \
  } while (0)

  // prologue: tile0 complete; AH0(1),B(1) in flight (4 loads)
  STAGE_AH(0, 0, 0);
  STAGE_BF(0, 0);
  STAGE_AH(0, 1, 0);
  STAGE_AH(1, 0, 64);
  STAGE_BF(1, 64);
  asm volatile("s_waitcnt vmcnt(4)" ::: "memory");
  __builtin_amdgcn_s_barrier();

  for (int t = 0; t < NT; ++t) {
    const int cur = t & 1;
    const u16* Ac = &As[cur][0];
    const u16* Bc = &Bs[cur][0];
    bf16x8 af[4][2], bv[2][2];

    // ph0: M-half 0. reads AH0+B; stage AH1(t+1)->nxt (slot free since
    // ph1(t-1)).
#pragma unroll
    for (int mi = 0; mi < 4; ++mi) {
      const int r = wm_ * 64 + mi * 16 + col;
#pragma unroll
      for (int ks = 0; ks < 2; ++ks)
        af[mi][ks] =
            *(const bf16x8*)&Ac[r * 64 + (((ks * 4 + quad) ^ (r & 7)) * 8)];
    }
#pragma unroll
    for (int ni = 0; ni < 2; ++ni) {
      const int r = wn_ * 32 + ni * 16 + col;
#pragma unroll
      for (int ks = 0; ks < 2; ++ks)
        bv[ni][ks] =
            *(const bf16x8*)&Bc[r * 64 + (((ks * 4 + quad) ^ (r & 7)) * 8)];
    }
    if (t + 1 < NT) STAGE_AH(cur ^ 1, 1, (t + 1) * 64);
    __builtin_amdgcn_s_barrier();
    asm volatile("s_waitcnt lgkmcnt(0)" ::: "memory");
    __builtin_amdgcn_s_setprio(1);
#pragma unroll
    for (int mi = 0; mi < 4; ++mi)
#pragma unroll
      for (int ni = 0; ni < 2; ++ni)
#pragma unroll
        for (int ks = 0; ks < 2; ++ks)
          acc[mi][ni] = __builtin_amdgcn_mfma_f32_16x16x32_bf16(
              af[mi][ks], bv[ni][ks], acc[mi][ni], 0, 0, 0);
    __builtin_amdgcn_s_setprio(0);
    if (t + 1 < NT)
      asm volatile("s_waitcnt vmcnt(6)" ::: "memory");  // forces AH1(t) done
    else
      asm volatile("s_waitcnt vmcnt(0)" ::: "memory");
    __builtin_amdgcn_s_barrier();

    // ph1: M-half 1. reads AH1; stage AH0(t+2),B(t+2)->cur (free since ph0).
#pragma unroll
    for (int mi = 0; mi < 4; ++mi) {
      const int r = 128 + wm_ * 64 + mi * 16 + col;
#pragma unroll
      for (int ks = 0; ks < 2; ++ks)
        af[mi][ks] =
            *(const bf16x8*)&Ac[r * 64 + (((ks * 4 + quad) ^ (r & 7)) * 8)];
    }
    if (t + 2 < NT) {
      STAGE_AH(cur, 0, (t + 2) * 64);
      STAGE_BF(cur, (t + 2) * 64);
    }
    __builtin_amdgcn_s_barrier();
    asm volatile("s_waitcnt lgkmcnt(0)" ::: "memory");
    __builtin_amdgcn_s_setprio(1);
#pragma unroll
    for (int mi = 0; mi < 4; ++mi)
#pragma unroll
      for (int ni = 0; ni < 2; ++ni)
#pragma unroll
        for (int ks = 0; ks < 2; ++ks)
          acc[4 + mi][ni] = __builtin_amdgcn_mfma_f32_16x16x32_bf16(
              af[mi][ks], bv[ni][ks], acc[4 + mi][ni], 0, 0, 0);
    __builtin_amdgcn_s_setprio(0);
    if (t + 2 < NT)
      asm volatile("s_waitcnt vmcnt(6)" ::: "memory");  // forces AH0,B(t+1)
    else if (t + 1 < NT)
      asm volatile("s_waitcnt vmcnt(2)" ::: "memory");
    __builtin_amdgcn_s_barrier();
  }
#undef STAGE_AH
#undef STAGE_BF

  // epilogue: row = m0 + mh*128 + wm_*64 + mi*16 + quad*4 + reg,
  //           col = n0 + wn_*32 + ni*16 + col
#pragma unroll
  for (int mh = 0; mh < 2; ++mh)
#pragma unroll
    for (int mi = 0; mi < 4; ++mi) {
      const int row = m0 + mh * 128 + wm_ * 64 + mi * 16 + quad * 4;
#pragma unroll
      for (int reg = 0; reg < 4; ++reg) {
#pragma unroll
        for (int ni = 0; ni < 2; ++ni) {
          const int cc = n0 + wn_ * 32 + ni * 16 + col;
          if (F32OUT)
            ((float*)Cv)[(size_t)(row + reg) * ldc + cc] =
                acc[mh * 4 + mi][ni][reg];
          else
            ((u16*)Cv)[(size_t)(row + reg) * ldc + cc] =
                f2bf(acc[mh * 4 + mi][ni][reg]);
        }
      }
    }
}

// MFMA flash attention, transposed-S (unchanged from R11).
__global__ __launch_bounds__(256) void attn_fwd(u16* __restrict__ qkv) {
  __shared__ u16 Ks[2][64 * 64];  // dbuf; row-linear, 16B-chunk XOR-swizzled
  __shared__ u16 Vt[64][72];      // [dim][key]
  __shared__ u16 Ps[64][72];      // [q][key]
  const int tid = threadIdx.x;
  const int w = tid >> 6, lane = tid & 63;
  const int col = lane & 15, quad = lane >> 4;
  const int bh = blockIdx.x;
  const int b = bh >> 4, h = bh & 15;
  const int pa = blockIdx.y;  // 0..15
  const size_t base = (size_t)(b * kT) * kNq + h * 64;

  const int krr = lane >> 3;
  const int ksw = (lane & 7) ^ krr;
  const u16* const kgbase =
      qkv + base + kD + (size_t)(w * 16 + krr) * kNq + ksw * 8;

  const int vkp = (tid & 31) * 2, vd0 = (tid >> 5) * 8;  // V staging
  const u16* const vgbase = qkv + base + 2 * kD + (size_t)vkp * kNq + vd0;

  bf16x8 onesf;  // all-ones B-frag: row-sum MFMA for the softmax denominator
#pragma unroll
  for (int i = 0; i < 8; ++i) onesf[i] = (short)0x3F80;

  int cur = 0;
#pragma unroll
  for (int pass = 0; pass < 2; ++pass) {
    const int qt = pass ? (31 - pa) : pa;
    const int q0 = qt << 6;

    bf16x8 aq[2];
#pragma unroll
    for (int ks = 0; ks < 2; ++ks)
      aq[ks] = *(const bf16x8*)(qkv + base + (size_t)(q0 + w * 16 + col) * kNq +
                                ks * 32 + quad * 8);

    gload16(kgbase, &Ks[cur][(w * 16) * 64]);
    gload16(kgbase + (size_t)8 * kNq, &Ks[cur][(w * 16 + 8) * 64]);
    uint4 va = *(const uint4*)vgbase;
    uint4 vb = *(const uint4*)(vgbase + kNq);

    f32x4 o[4];  // O[q=w*16+quad*4+reg][d=nt*16+col]
#pragma unroll
    for (int nt = 0; nt < 4; ++nt) o[nt] = (f32x4){0.f, 0.f, 0.f, 0.f};
    f32x4 o4 = (f32x4){0.f, 0.f, 0.f, 0.f};  // l for q=w*16+quad*4+reg

    for (int kt = 0; kt <= qt; ++kt) {
      __syncthreads();  // drains K-DMA(kt)+V-loads(kt); prior tile reads done
      {  // write Vt(kt): v_perm_b32 packs key-pair words
        const unsigned int* aw = (const unsigned int*)&va;
        const unsigned int* bw = (const unsigned int*)&vb;
#pragma unroll
        for (int i = 0; i < 4; ++i) {
          *(unsigned int*)&Vt[vd0 + 2 * i][vkp] =
              __builtin_amdgcn_perm(bw[i], aw[i], 0x05040100u);
          *(unsigned int*)&Vt[vd0 + 2 * i + 1][vkp] =
              __builtin_amdgcn_perm(bw[i], aw[i], 0x07060302u);
        }
      }
      __syncthreads();  // Vt(kt) + Ks[cur] visible to all waves

      if (kt < qt) {  // prefetch kt+1; latency hides under QK/softmax/PV
        const size_t ko = (size_t)((kt + 1) << 6) * kNq;
        gload16(kgbase + ko, &Ks[cur ^ 1][(w * 16) * 64]);
        gload16(kgbase + ko + (size_t)8 * kNq, &Ks[cur ^ 1][(w * 16 + 8) * 64]);
        va = *(const uint4*)(vgbase + ko);
        vb = *(const uint4*)(vgbase + ko + kNq);
      }

      // St = K Q^T : rows = 64 keys (4 nt frags), cols = wave's 16 q
      f32x4 st[4];
#pragma unroll
      for (int nt = 0; nt < 4; ++nt) st[nt] = (f32x4){0.f, 0.f, 0.f, 0.f};
#pragma unroll
      for (int ks = 0; ks < 2; ++ks) {
#pragma unroll
        for (int nt = 0; nt < 4; ++nt) {
          const int kr = nt * 16 + col;  // key row
          const bf16x8 bk = *(const bf16x8*)&Ks[cur][kr * 64 +
                                                     (((ks * 4 + quad) ^
                                                       (col & 7)) *
                                                      8)];
          st[nt] = __builtin_amdgcn_mfma_f32_16x16x32_bf16(bk, aq[ks], st[nt],
                                                           0, 0, 0);
        }
      }

      // p = exp2(st) via raw hw exp2 (bounded logits); mask diagonal tile
      if (kt == qt) {
        const int qrel = w * 16 + col;
#pragma unroll
        for (int nt = 0; nt < 4; ++nt)
#pragma unroll
          for (int reg = 0; reg < 4; ++reg) {
            const int krel = nt * 16 + quad * 4 + reg;
            st[nt][reg] =
                (krel <= qrel) ? __builtin_amdgcn_exp2f(st[nt][reg]) : 0.f;
          }
      } else {
#pragma unroll
        for (int nt = 0; nt < 4; ++nt)
#pragma unroll
          for (int reg = 0; reg < 4; ++reg)
            st[nt][reg] = __builtin_amdgcn_exp2f(st[nt][reg]);
      }

      // P -> Ps[q][k]: per nt, 4 consecutive k -> one b64 write (cvt_pk pack)
#pragma unroll
      for (int nt = 0; nt < 4; ++nt) {
        uint2 pk;
        pk.x = cvtpk(st[nt][0], st[nt][1]);
        pk.y = cvtpk(st[nt][2], st[nt][3]);
        *(uint2*)&Ps[w * 16 + col][nt * 16 + quad * 4] = pk;
      }

      // O += P V; l += P 1 (same-wave Ps band roundtrip, no barrier needed)
#pragma unroll
      for (int ks = 0; ks < 2; ++ks) {
        const bf16x8 ap =
            *(const bf16x8*)&Ps[w * 16 + col][ks * 32 + quad * 8];
#pragma unroll
        for (int nt = 0; nt < 4; ++nt) {
          const bf16x8 bv =
              *(const bf16x8*)&Vt[nt * 16 + col][ks * 32 + quad * 8];
          o[nt] = __builtin_amdgcn_mfma_f32_16x16x32_bf16(ap, bv, o[nt], 0, 0,
                                                          0);
        }
        o4 = __builtin_amdgcn_mfma_f32_16x16x32_bf16(ap, onesf, o4, 0, 0, 0);
      }
      cur ^= 1;
    }

    // epilogue: o row q = w*16+quad*4+reg; l = o4[reg] (replicated over cols)
#pragma unroll
    for (int reg = 0; reg < 4; ++reg) {
      const float inv = 1.0f / o4[reg];
      u16* yp = qkv + base + (size_t)(q0 + w * 16 + quad * 4 + reg) * kNq;
#pragma unroll
      for (int nt = 0; nt < 4; ++nt)
        yp[nt * 16 + col] = f2bf(o[nt][reg] * inv);
    }
  }
}

extern "C" void kernel_launch(void* const* d_in, const int* in_sizes, int n_in,
                              void* d_out, int out_size, void* d_ws,
                              size_t ws_size, hipStream_t stream) {
  const float* x = (const float*)d_in[0];      // [8192][1024] fp32
  const float* w_qkv = (const float*)d_in[1];  // [1024][3072] fp32
  const float* w_out = (const float*)d_in[2];  // [1024][1024] fp32

  u16* wqkvT = (u16*)d_ws;                // [3072][1024] bf16  6.3MB
  u16* woutT = wqkvT + (size_t)kNq * kD;  // [1024][1024] bf16  2.1MB
  u16* qkvb = woutT + (size_t)kD * kD;    // [8192][3072] bf16 50.3MB
  u16* xb = (u16*)d_out;  // x as bf16 in d_out bytes (dead after qkv gemm)

  cvt_bf16<<<kM * kD / 2048, 256, 0, stream>>>(x, xb);
  transpose_bf<<<dim3(kNq / 32, kD / 32), 256, 0, stream>>>(w_qkv, wqkvT, kD,
                                                            kNq, kD);
  transpose_bf<<<dim3(kD / 32, kD / 32), 256, 0, stream>>>(w_out, woutT, kD,
                                                           kD, 0);
  gemm_mt<false><<<dim3(kNq / 128, kM / 256), 512, 0, stream>>>(xb, wqkvT,
                                                                qkvb, kD, kNq);
  attn_fwd<<<dim3(kB * kH, 16), 256, 0, stream>>>(qkvb);
  gemm_mt<true><<<dim3(kD / 128, kM / 256), 512, 0, stream>>>(qkvb, woutT,
                                                              d_out, kNq, kD);
}